// Round 2
// baseline (158.845 us; speedup 1.0000x reference)
//
#include <hip/hip_runtime.h>

// 4-layer MLP: [B,64] -> 4 -> 8 -> 8 -> 32, sigmoid each layer. All f32.
// Memory-bound: 256 MB read + 128 MB write -> ~61 us floor @ 6.3 TB/s.
//
// R1 lesson: per-thread row reads (256 B lane stride) thrash L1 (16 B used
// per 128 B line per instr; working set > L1) -> latency-bound at 2.3 TB/s.
// R2: stage 256-row x-tile in LDS with coalesced loads + XOR-swizzled slots
// (slot = row*16 + (c ^ (row&15)), balanced 8 lanes / 4-bank group both ways).

#define IN_DIM 64
#define OUT_DIM 32
#define THREADS 256
#define TILE_ROWS 256

__device__ __forceinline__ float fast_sigmoid(float z) {
    float e = __expf(-z);
    return __builtin_amdgcn_rcpf(1.0f + e);
}

__global__ __launch_bounds__(256) void mlp4_kernel(
    const float* __restrict__ x,
    const float* __restrict__ W0, const float* __restrict__ b0,
    const float* __restrict__ W1, const float* __restrict__ b1,
    const float* __restrict__ W2, const float* __restrict__ b2,
    const float* __restrict__ W3, const float* __restrict__ b3,
    float* __restrict__ out, int batch)
{
    // x tile: 256 rows x 16 float4 = 64 KB, XOR-swizzled within each row.
    __shared__ float4 sx[TILE_ROWS * 16];
    // weights/biases (~2.6 KB)
    __shared__ float sW0[4 * 64];
    __shared__ float sb0[4];
    __shared__ float sW1[8 * 4];
    __shared__ float sb1[8];
    __shared__ float sW2[8 * 8];
    __shared__ float sb2[8];
    __shared__ float sW3[32 * 8];
    __shared__ float sb3[32];

    const int tid = threadIdx.x;
    sW0[tid] = W0[tid];
    sW3[tid] = W3[tid];
    if (tid < 64) sW2[tid] = W2[tid];
    if (tid < 32) { sW1[tid] = W1[tid]; sb3[tid] = b3[tid]; }
    if (tid < 8)  { sb1[tid] = b1[tid]; sb2[tid] = b2[tid]; }
    if (tid < 4)  { sb0[tid] = b0[tid]; }

    // ---- Stage x tile: fully coalesced (256 consecutive float4 per instr) ----
    const long long tileBase = (long long)blockIdx.x * TILE_ROWS;   // first row
    const long long chunkBase = tileBase * (IN_DIM / 4);            // first float4
    const long long totalChunks = (long long)batch * (IN_DIM / 4);
    const float4* xg = reinterpret_cast<const float4*>(x);
    #pragma unroll
    for (int k = 0; k < 16; ++k) {
        const int l = tid + THREADS * k;      // 0..4095 tile-local float4 index
        const int r = l >> 4;                 // tile-local row
        const int c = l & 15;                 // chunk within row
        const long long g = chunkBase + l;
        float4 v = make_float4(0.f, 0.f, 0.f, 0.f);
        if (g < totalChunks) v = xg[g];
        sx[(r << 4) | (c ^ (r & 15))] = v;    // swizzled slot
    }
    __syncthreads();

    const long long row = tileBase + tid;
    if (row >= batch) return;

    // ---- Read own row from LDS (swizzled, conflict-balanced b128 reads) ----
    float xr[IN_DIM];
    #pragma unroll
    for (int c = 0; c < 16; ++c) {
        float4 v = sx[(tid << 4) | (c ^ (tid & 15))];
        xr[4 * c + 0] = v.x;
        xr[4 * c + 1] = v.y;
        xr[4 * c + 2] = v.z;
        xr[4 * c + 3] = v.w;
    }

    // ---- Layer 0: 64 -> 4 ----
    float h0[4];
    #pragma unroll
    for (int cc = 0; cc < 4; ++cc) {
        float acc = sb0[cc];
        #pragma unroll
        for (int k = 0; k < IN_DIM; ++k)
            acc = fmaf(xr[k], sW0[cc * IN_DIM + k], acc);
        h0[cc] = fast_sigmoid(acc);
    }

    // ---- Layer 1: 4 -> 8 ----
    float h1[8];
    #pragma unroll
    for (int j = 0; j < 8; ++j) {
        float acc = sb1[j];
        #pragma unroll
        for (int cc = 0; cc < 4; ++cc)
            acc = fmaf(h0[cc], sW1[j * 4 + cc], acc);
        h1[j] = fast_sigmoid(acc);
    }

    // ---- Layer 2: 8 -> 8 ----
    float h2[8];
    #pragma unroll
    for (int j = 0; j < 8; ++j) {
        float acc = sb2[j];
        #pragma unroll
        for (int i = 0; i < 8; ++i)
            acc = fmaf(h1[i], sW2[j * 8 + i], acc);
        h2[j] = fast_sigmoid(acc);
    }

    // ---- Layer 3: 8 -> 32, store as 8x float4 ----
    float4* op = reinterpret_cast<float4*>(out + (size_t)row * OUT_DIM);
    #pragma unroll
    for (int q = 0; q < OUT_DIM / 4; ++q) {
        float o[4];
        #pragma unroll
        for (int r2 = 0; r2 < 4; ++r2) {
            const int oidx = q * 4 + r2;
            float acc = sb3[oidx];
            #pragma unroll
            for (int j = 0; j < 8; ++j)
                acc = fmaf(h2[j], sW3[oidx * 8 + j], acc);
            o[r2] = fast_sigmoid(acc);
        }
        op[q] = make_float4(o[0], o[1], o[2], o[3]);
    }
}

extern "C" void kernel_launch(void* const* d_in, const int* in_sizes, int n_in,
                              void* d_out, int out_size, void* d_ws, size_t ws_size,
                              hipStream_t stream) {
    const float* x  = (const float*)d_in[0];
    const float* W0 = (const float*)d_in[1];
    const float* b0 = (const float*)d_in[2];
    const float* W1 = (const float*)d_in[3];
    const float* b1 = (const float*)d_in[4];
    const float* W2 = (const float*)d_in[5];
    const float* b2 = (const float*)d_in[6];
    const float* W3 = (const float*)d_in[7];
    const float* b3 = (const float*)d_in[8];
    float* out = (float*)d_out;

    const int batch = in_sizes[0] / IN_DIM;  // 1,000,000
    const int blocks = (batch + TILE_ROWS - 1) / TILE_ROWS;

    mlp4_kernel<<<blocks, THREADS, 0, stream>>>(x, W0, b0, W1, b1, W2, b2, W3, b3,
                                                out, batch);
}

// Round 3
// 95.313 us; speedup vs baseline: 1.6666x; 1.6666x over previous
//
#include <hip/hip_runtime.h>
#include <cstdint>

// 4-layer MLP: [B,64] -> 4 -> 8 -> 8 -> 32, sigmoid each layer. All f32.
// HBM floor: 256 MB read + 128 MB write -> ~61 us @ 6.3 TB/s (less w/ L3 hits).
//
// R1: per-thread row reads, VGPR=32 -> 1 load in flight, 8x L1<->L2 line
//     amplification -> 2.3 TB/s, 145 us.
// R2: LDS tile via VGPR round-trip + __syncthreads -> staging serialized,
//     occupancy 21% -> 1.4 TB/s, 184 us.
// R3: wave-local fire-and-forget staging with global_load_lds(16B):
//     16 instrs -> one vmcnt(0) -> compute. No block barrier in main path.
//     LDS dest is linear (HW: base + lane*16); bank-conflict-free readback
//     achieved by XOR-pre-swizzling the GLOBAL source address (rule 21):
//     slot p=(r<<4)|c' holds chunk c'^(r&15) of row r -> readback
//     ds_read_b128 lands 8 lanes per 4-bank group (balanced; minimum depth).

#define IN_DIM 64
#define OUT_DIM 32
#define THREADS 256
#define WAVES_PER_BLOCK 4
#define ROWS_PER_WAVE 64

__device__ __forceinline__ float fast_sigmoid(float z) {
    float e = __expf(-z);
    return __builtin_amdgcn_rcpf(1.0f + e);
}

__global__ __launch_bounds__(THREADS) void mlp4_kernel(
    const float* __restrict__ x,
    const float* __restrict__ W0, const float* __restrict__ b0,
    const float* __restrict__ W1, const float* __restrict__ b1,
    const float* __restrict__ W2, const float* __restrict__ b2,
    const float* __restrict__ W3, const float* __restrict__ b3,
    float* __restrict__ out, int batch)
{
    // Per-wave x tiles: 4 waves x 1024 float4 (16 KB each) = 64 KB, linear dest.
    __shared__ float4 sx[WAVES_PER_BLOCK * 1024];
    // Weights/biases (~2.6 KB).
    __shared__ float sW0[4 * 64];
    __shared__ float sb0[4];
    __shared__ float sW1[8 * 4];
    __shared__ float sb1[8];
    __shared__ float sW2[8 * 8];
    __shared__ float sb2[8];
    __shared__ float sW3[32 * 8];
    __shared__ float sb3[32];

    const int tid = threadIdx.x;
    sW0[tid] = W0[tid];
    sW3[tid] = W3[tid];
    if (tid < 64) sW2[tid] = W2[tid];
    if (tid < 32) { sW1[tid] = W1[tid]; sb3[tid] = b3[tid]; }
    if (tid < 8)  { sb1[tid] = b1[tid]; sb2[tid] = b2[tid]; }
    if (tid < 4)  { sb0[tid] = b0[tid]; }
    __syncthreads();   // weights visible to all waves; only barrier in kernel

    const int wave = tid >> 6;
    const int lane = tid & 63;
    const long long waveRow0 =
        ((long long)blockIdx.x * WAVES_PER_BLOCK + wave) * ROWS_PER_WAVE;
    if (waveRow0 >= batch) return;   // whole-wave uniform

    const int wbase = wave << 10;    // this wave's float4 slot base in sx

    // ---- Stage 64 rows: 16x global_load_lds (1 KB each), source pre-swizzled.
    // Wave-local slot p = 64k + lane; r = p>>4, store chunk c = (p&15)^(r&15).
    // Per 16-lane group the addresses permute within ONE contiguous 256 B row
    // -> perfectly coalesced. Tail safety: clamp row (batch is exact anyway).
    const float4* xg = reinterpret_cast<const float4*>(x);
    #pragma unroll
    for (int k = 0; k < 16; ++k) {
        const int p = (k << 6) | lane;
        const int r = p >> 4;
        const int c = (p & 15) ^ (r & 15);
        long long row = waveRow0 + r;
        if (row >= batch) row = batch - 1;           // clamp, stay in-bounds
        const float4* src = xg + row * 16 + c;
        // wave-uniform LDS base for this instr; HW adds lane*16
        __builtin_amdgcn_global_load_lds(
            reinterpret_cast<const uint32_t*>(src),
            reinterpret_cast<uint32_t*>(&sx[wbase + (k << 6)]),
            16, 0, 0);
    }
    asm volatile("s_waitcnt vmcnt(0)" ::: "memory");
    __builtin_amdgcn_sched_barrier(0);   // don't let LDS reads cross the wait

    // ---- Compute: one row per lane, x consumed chunk-wise from LDS ----
    const int myRowSlots = wbase | (lane << 4);
    const int rx = lane & 15;

    float acc[4] = {sb0[0], sb0[1], sb0[2], sb0[3]};
    #pragma unroll
    for (int c = 0; c < 16; ++c) {
        const float4 xv = sx[myRowSlots | (c ^ rx)];
        #pragma unroll
        for (int o = 0; o < 4; ++o) {
            const float4 wv = *reinterpret_cast<const float4*>(&sW0[o * 64 + 4 * c]);
            acc[o] = fmaf(xv.x, wv.x, acc[o]);
            acc[o] = fmaf(xv.y, wv.y, acc[o]);
            acc[o] = fmaf(xv.z, wv.z, acc[o]);
            acc[o] = fmaf(xv.w, wv.w, acc[o]);
        }
    }
    float h0[4];
    #pragma unroll
    for (int o = 0; o < 4; ++o) h0[o] = fast_sigmoid(acc[o]);

    // ---- Layer 1: 4 -> 8 ----
    float h1[8];
    #pragma unroll
    for (int j = 0; j < 8; ++j) {
        float a = sb1[j];
        #pragma unroll
        for (int c = 0; c < 4; ++c) a = fmaf(h0[c], sW1[j * 4 + c], a);
        h1[j] = fast_sigmoid(a);
    }

    // ---- Layer 2: 8 -> 8 ----
    float h2[8];
    #pragma unroll
    for (int j = 0; j < 8; ++j) {
        float a = sb2[j];
        #pragma unroll
        for (int i = 0; i < 8; ++i) a = fmaf(h1[i], sW2[j * 8 + i], a);
        h2[j] = fast_sigmoid(a);
    }

    // ---- Layer 3: 8 -> 32, store 8x float4 ----
    const long long row = waveRow0 + lane;
    if (row < batch) {
        float4* op = reinterpret_cast<float4*>(out + (size_t)row * OUT_DIM);
        #pragma unroll
        for (int q = 0; q < OUT_DIM / 4; ++q) {
            float o4[4];
            #pragma unroll
            for (int r2 = 0; r2 < 4; ++r2) {
                const int oidx = q * 4 + r2;
                float a = sb3[oidx];
                #pragma unroll
                for (int j = 0; j < 8; ++j) a = fmaf(h2[j], sW3[oidx * 8 + j], a);
                o4[r2] = fast_sigmoid(a);
            }
            op[q] = make_float4(o4[0], o4[1], o4[2], o4[3]);
        }
    }
}

extern "C" void kernel_launch(void* const* d_in, const int* in_sizes, int n_in,
                              void* d_out, int out_size, void* d_ws, size_t ws_size,
                              hipStream_t stream) {
    const float* x  = (const float*)d_in[0];
    const float* W0 = (const float*)d_in[1];
    const float* b0 = (const float*)d_in[2];
    const float* W1 = (const float*)d_in[3];
    const float* b1 = (const float*)d_in[4];
    const float* W2 = (const float*)d_in[5];
    const float* b2 = (const float*)d_in[6];
    const float* W3 = (const float*)d_in[7];
    const float* b3 = (const float*)d_in[8];
    float* out = (float*)d_out;

    const int batch = in_sizes[0] / IN_DIM;  // 1,000,000
    const long long waves = ((long long)batch + ROWS_PER_WAVE - 1) / ROWS_PER_WAVE;
    const int blocks = (int)((waves + WAVES_PER_BLOCK - 1) / WAVES_PER_BLOCK);

    mlp4_kernel<<<blocks, THREADS, 0, stream>>>(x, W0, b0, W1, b1, W2, b2, W3, b3,
                                                out, batch);
}